// Round 1
// baseline (173.633 us; speedup 1.0000x reference)
//
#include <hip/hip_runtime.h>

// YOLOv3 detector decode, 3 scales fused into one launch.
// Layout: in[b, a*85+d, h, w]; boxes row = scale_base + ((b*H+h)*W + w)*3 + a.
// grid = (nb13+nb26+nb52, 3): grid.y = anchor, so consecutive threads read
// consecutive hw -> every channel load is a fully coalesced wave transaction.

#define NCLS 80

template<int H, int W>
__device__ __forceinline__ void decode_scale(
    const float* __restrict__ in, const float* __restrict__ anch,
    float scale, float inv_case, float th,
    int a, int cell, int row_base,
    float* __restrict__ boxes, float* __restrict__ mask)
{
    constexpr int HW = H * W;
    int b  = cell / HW;          // compile-time divisor -> magic mul
    int hw = cell - b * HW;
    int h  = hw / W;
    int w  = hw - h * W;

    const float* p = in + ((size_t)b * 255 + (size_t)a * 85) * HW + hw;

    float o0 = p[0 * HW];
    float o1 = p[1 * HW];
    float o2 = p[2 * HW];
    float o3 = p[3 * HW];
    float o4 = p[4 * HW];

    // argmax over classes d = 5..84 (first-max wins: strict >)
    float best = p[5 * HW];
    int   bi   = 0;
#pragma unroll 8
    for (int d = 1; d < NCLS; ++d) {
        float v = p[(5 + d) * HW];
        if (v > best) { best = v; bi = d; }
    }

    float px = 1.0f / (1.0f + __expf(-o0));
    float cx = ((float)w + o1) * scale;
    float cy = ((float)h + o2) * scale;
    float bw = anch[2 * a + 0] * __expf(o3) * inv_case;
    float bh = anch[2 * a + 1] * __expf(o4) * inv_case;

    int row = row_base + cell * 3 + a;
    float* ob = boxes + (size_t)row * 6;
    ob[0] = px;
    ob[1] = cx;
    ob[2] = cy;
    ob[3] = bw;
    ob[4] = bh;
    ob[5] = (float)bi;
    mask[row] = (o0 > th) ? 1.0f : 0.0f;
}

__global__ __launch_bounds__(256) void detector_kernel(
    const float* __restrict__ in13, const float* __restrict__ in26,
    const float* __restrict__ in52,
    const float* __restrict__ a13, const float* __restrict__ a26,
    const float* __restrict__ a52,
    const float* __restrict__ thp, const int* __restrict__ casep,
    float* __restrict__ boxes, float* __restrict__ mask,
    int B, int nb13, int nb26)
{
    const int a  = blockIdx.y;
    const int bx = blockIdx.x;
    const float th       = thp[0];
    const float inv_case = 1.0f / (float)casep[0];

    if (bx < nb13) {
        int cell = bx * 256 + threadIdx.x;
        if (cell < B * 169)
            decode_scale<13, 13>(in13, a13, 32.0f * inv_case, inv_case, th,
                                 a, cell, 0, boxes, mask);
    } else if (bx < nb13 + nb26) {
        int cell = (bx - nb13) * 256 + threadIdx.x;
        if (cell < B * 676)
            decode_scale<26, 26>(in26, a26, 16.0f * inv_case, inv_case, th,
                                 a, cell, B * 169 * 3, boxes, mask);
    } else {
        int cell = (bx - nb13 - nb26) * 256 + threadIdx.x;
        if (cell < B * 2704)
            decode_scale<52, 52>(in52, a52, 8.0f * inv_case, inv_case, th,
                                 a, cell, B * (169 + 676) * 3, boxes, mask);
    }
}

extern "C" void kernel_launch(void* const* d_in, const int* in_sizes, int n_in,
                              void* d_out, int out_size, void* d_ws, size_t ws_size,
                              hipStream_t stream) {
    const float* in13 = (const float*)d_in[0];
    const float* in26 = (const float*)d_in[1];
    const float* in52 = (const float*)d_in[2];
    const float* a13  = (const float*)d_in[3];
    const float* a26  = (const float*)d_in[4];
    const float* a52  = (const float*)d_in[5];
    const float* thp  = (const float*)d_in[6];
    const int*   casep = (const int*)d_in[7];

    const int B = in_sizes[0] / (255 * 169);

    const int nb13 = (B * 169  + 255) / 256;
    const int nb26 = (B * 676  + 255) / 256;
    const int nb52 = (B * 2704 + 255) / 256;

    const int nrows = B * (169 + 676 + 2704) * 3;
    float* boxes = (float*)d_out;
    float* mask  = (float*)d_out + (size_t)nrows * 6;

    dim3 grid(nb13 + nb26 + nb52, 3);
    detector_kernel<<<grid, 256, 0, stream>>>(
        in13, in26, in52, a13, a26, a52, thp, casep,
        boxes, mask, B, nb13, nb26);
}